// Round 7
// baseline (451.651 us; speedup 1.0000x reference)
//
#include <hip/hip_runtime.h>
#include <math.h>

#define S_LEN 2048
#define DIM   2048
#define NH    16
#define NKV   8
#define HD    128
#define SKETCH 64
#define KV_DIM 1024
// softmax in base-2: fold log2(e) into the score scale
#define SCALE (0.08838834764831845f * 1.4426950408889634f)

typedef _Float16 half8_t  __attribute__((ext_vector_type(8)));
typedef __bf16   bf8_t    __attribute__((ext_vector_type(8)));
typedef __bf16   bf4_t    __attribute__((ext_vector_type(4)));
typedef float    f32x16_t __attribute__((ext_vector_type(16)));
typedef unsigned int uint4_t __attribute__((ext_vector_type(4)));

// ---------------------------------------------------------------------------
// Fused sb_mfma + as_mfma3.  grid(640):
//  x < 384: SB_t[b][k][m] = sum_d S_t[b][d][k] * W_t[m][d]  (atomicAdd, K-split 4)
//  x >= 384: AS_t[row][64] += (1/64) * X[row][:] @ S_t[b][:][:], t in {q,k,v}
// Both roles use the same 55296-byte LDS footprint.
// ---------------------------------------------------------------------------
__global__ __launch_bounds__(256) void sbas_mfma(
    const float* __restrict__ x,
    const float* __restrict__ Sq, const float* __restrict__ Sk,
    const float* __restrict__ Sv, const float* __restrict__ So,
    const float* __restrict__ wq, const float* __restrict__ wk,
    const float* __restrict__ wv, const float* __restrict__ wo,
    float* __restrict__ SBq, float* __restrict__ SBk,
    float* __restrict__ SBv, float* __restrict__ SBo,
    float* __restrict__ ASq, float* __restrict__ ASk,
    float* __restrict__ ASv) {
  __shared__ __align__(16) char smem[55296];
  const int tid = threadIdx.x, ln = tid & 63, w = tid >> 6;
  const int l31 = ln & 31, h32 = ln >> 5;
  const int bx = blockIdx.x;

  if (bx < 384) {
    // ---------------- SB role ----------------
    const int bt = bx % 96, kc = bx / 96;
    const float *Ss, *W;
    float* SB;
    int Mout, n0;
    if (bt < 32)      { Ss = Sq; W = wq; SB = SBq; Mout = DIM;    n0 = bt * 64; }
    else if (bt < 48) { Ss = Sk; W = wk; SB = SBk; Mout = KV_DIM; n0 = (bt - 32) * 64; }
    else if (bt < 64) { Ss = Sv; W = wv; SB = SBv; Mout = KV_DIM; n0 = (bt - 48) * 64; }
    else              { Ss = So; W = wo; SB = SBo; Mout = DIM;    n0 = (bt - 64) * 64; }

    __bf16* Sth = (__bf16*)smem;        // [2][64][72]
    __bf16* Stl = Sth + 9216;
    __bf16* Wh  = Stl + 9216;           // [64][72]
    __bf16* Wl  = Wh + 4608;

    const int bw = w >> 1, mt = w & 1;
    f32x16_t acc[2];
#pragma unroll
    for (int ns = 0; ns < 2; ++ns)
#pragma unroll
      for (int r = 0; r < 16; ++r) acc[ns][r] = 0.0f;

    const int dbeg = kc * 512;
    for (int d0 = dbeg; d0 < dbeg + 512; d0 += 64) {
#pragma unroll
      for (int it = 0; it < 8; ++it) {
        int i = tid + it * 256;
        int b2 = i >> 10, rem = i & 1023;
        int d = rem >> 4, c4 = (rem & 15) << 2;
        float4 v = *(const float4*)(Ss + ((size_t)b2 * DIM + d0 + d) * SKETCH + c4);
        float vv[4] = {v.x, v.y, v.z, v.w};
#pragma unroll
        for (int j = 0; j < 4; ++j) {
          __bf16 hh = (__bf16)vv[j];
          Sth[(b2 * 64 + c4 + j) * 72 + d] = hh;
          Stl[(b2 * 64 + c4 + j) * 72 + d] = (__bf16)(vv[j] - (float)hh);
        }
      }
#pragma unroll
      for (int it = 0; it < 4; ++it) {
        int i = tid + it * 256;
        int c = i >> 4, d4 = (i & 15) << 2;
        float4 v = *(const float4*)(W + (size_t)(n0 + c) * DIM + d0 + d4);
        bf4_t hx, lx;
        float vv[4] = {v.x, v.y, v.z, v.w};
#pragma unroll
        for (int j = 0; j < 4; ++j) {
          __bf16 hh = (__bf16)vv[j];
          hx[j] = hh; lx[j] = (__bf16)(vv[j] - (float)hh);
        }
        *(bf4_t*)&Wh[c * 72 + d4] = hx;
        *(bf4_t*)&Wl[c * 72 + d4] = lx;
      }
      __syncthreads();
#pragma unroll
      for (int ks = 0; ks < 4; ++ks) {
        bf8_t ah = *(const bf8_t*)&Sth[(bw * 64 + mt * 32 + l31) * 72 + ks * 16 + h32 * 8];
        bf8_t al = *(const bf8_t*)&Stl[(bw * 64 + mt * 32 + l31) * 72 + ks * 16 + h32 * 8];
#pragma unroll
        for (int ns = 0; ns < 2; ++ns) {
          bf8_t bh_ = *(const bf8_t*)&Wh[(ns * 32 + l31) * 72 + ks * 16 + h32 * 8];
          bf8_t bl_ = *(const bf8_t*)&Wl[(ns * 32 + l31) * 72 + ks * 16 + h32 * 8];
          acc[ns] = __builtin_amdgcn_mfma_f32_32x32x16_bf16(ah, bh_, acc[ns], 0, 0, 0);
          acc[ns] = __builtin_amdgcn_mfma_f32_32x32x16_bf16(al, bh_, acc[ns], 0, 0, 0);
          acc[ns] = __builtin_amdgcn_mfma_f32_32x32x16_bf16(ah, bl_, acc[ns], 0, 0, 0);
        }
      }
      __syncthreads();
    }
#pragma unroll
    for (int ns = 0; ns < 2; ++ns)
#pragma unroll
      for (int r = 0; r < 16; ++r) {
        int kk = mt * 32 + (r & 3) + 8 * (r >> 2) + 4 * h32;
        atomicAdd(&SB[((size_t)bw * SKETCH + kk) * Mout + n0 + ns * 32 + l31], acc[ns][r]);
      }
  } else {
    // ---------------- AS role ----------------
    const int idx = bx - 384;
    const int rt = idx >> 3, kc = idx & 7;
    const int row0 = rt * 128;
    const int bb = row0 >> 11;

    __bf16* Xh  = (__bf16*)smem;        // [128][72]
    __bf16* Xl  = Xh + 9216;
    __bf16* S2h = Xl + 9216;            // [64][72]
    __bf16* S2l = S2h + 4608;

    const float* Sp[3] = {Sq + (size_t)bb * DIM * SKETCH,
                          Sk + (size_t)bb * DIM * SKETCH,
                          Sv + (size_t)bb * DIM * SKETCH};
    float* Op[3] = {ASq, ASk, ASv};

    f32x16_t acc[3][2];
#pragma unroll
    for (int t = 0; t < 3; ++t)
#pragma unroll
      for (int nt = 0; nt < 2; ++nt)
#pragma unroll
        for (int r = 0; r < 16; ++r) acc[t][nt][r] = 0.0f;

    const int kbeg = kc * 256;
    for (int k0 = kbeg; k0 < kbeg + 256; k0 += 64) {
#pragma unroll
      for (int it = 0; it < 8; ++it) {
        int i = tid + it * 256;
        int r = i >> 4, c4 = (i & 15) << 2;
        float4 v = *(const float4*)(x + (size_t)(row0 + r) * DIM + k0 + c4);
        bf4_t hx, lx;
        float vv[4] = {v.x, v.y, v.z, v.w};
#pragma unroll
        for (int j = 0; j < 4; ++j) {
          __bf16 hh = (__bf16)vv[j];
          hx[j] = hh; lx[j] = (__bf16)(vv[j] - (float)hh);
        }
        *(bf4_t*)&Xh[r * 72 + c4] = hx;
        *(bf4_t*)&Xl[r * 72 + c4] = lx;
      }
#pragma unroll
      for (int t = 0; t < 3; ++t) {
#pragma unroll
        for (int it = 0; it < 4; ++it) {
          int i = tid + it * 256;
          int r = i & 63, c4 = (i >> 6) << 2;
          float4 v = *(const float4*)(Sp[t] + (size_t)(k0 + r) * SKETCH + c4);
          float vv[4] = {v.x, v.y, v.z, v.w};
#pragma unroll
          for (int j = 0; j < 4; ++j) {
            __bf16 hh = (__bf16)vv[j];
            S2h[(c4 + j) * 72 + r] = hh;
            S2l[(c4 + j) * 72 + r] = (__bf16)(vv[j] - (float)hh);
          }
        }
        __syncthreads();
#pragma unroll
        for (int ks = 0; ks < 4; ++ks) {
          bf8_t ah = *(const bf8_t*)&Xh[(w * 32 + l31) * 72 + ks * 16 + h32 * 8];
          bf8_t al = *(const bf8_t*)&Xl[(w * 32 + l31) * 72 + ks * 16 + h32 * 8];
#pragma unroll
          for (int nt = 0; nt < 2; ++nt) {
            bf8_t bh_ = *(const bf8_t*)&S2h[(nt * 32 + l31) * 72 + ks * 16 + h32 * 8];
            bf8_t bl_ = *(const bf8_t*)&S2l[(nt * 32 + l31) * 72 + ks * 16 + h32 * 8];
            acc[t][nt] = __builtin_amdgcn_mfma_f32_32x32x16_bf16(ah, bh_, acc[t][nt], 0, 0, 0);
            acc[t][nt] = __builtin_amdgcn_mfma_f32_32x32x16_bf16(al, bh_, acc[t][nt], 0, 0, 0);
            acc[t][nt] = __builtin_amdgcn_mfma_f32_32x32x16_bf16(ah, bl_, acc[t][nt], 0, 0, 0);
          }
        }
        __syncthreads();
      }
    }
#pragma unroll
    for (int t = 0; t < 3; ++t)
#pragma unroll
      for (int nt = 0; nt < 2; ++nt)
#pragma unroll
        for (int r = 0; r < 16; ++r) {
          int row = row0 + w * 32 + (r & 3) + 8 * (r >> 2) + 4 * h32;
          atomicAdd(&Op[t][(size_t)row * SKETCH + nt * 32 + l31],
                    acc[t][nt][r] * (1.0f / 64.0f));
        }
  }
}

// ---------------------------------------------------------------------------
// as_mfma: single-matrix version (ATT @ So), unchanged.
// ---------------------------------------------------------------------------
__global__ __launch_bounds__(256) void as_mfma(
    const float* __restrict__ X, const float* __restrict__ S,
    float* __restrict__ OUT) {
  const int rt = blockIdx.x, kc = blockIdx.y;
  const int row0 = rt * 128;
  const int bb = row0 >> 11;
  const float* Sb = S + (size_t)bb * DIM * SKETCH;
  const int tid = threadIdx.x, ln = tid & 63, w = tid >> 6;
  const int l31 = ln & 31, h32 = ln >> 5;

  __shared__ __bf16 Xh[128][72], Xl[128][72];
  __shared__ __bf16 Sth[64][72], Stl[64][72];

  f32x16_t acc[2];
#pragma unroll
  for (int nt = 0; nt < 2; ++nt)
#pragma unroll
    for (int r = 0; r < 16; ++r) acc[nt][r] = 0.0f;

  const int kbeg = kc * 256;
  for (int k0 = kbeg; k0 < kbeg + 256; k0 += 64) {
#pragma unroll
    for (int it = 0; it < 8; ++it) {
      int idx = tid + it * 256;
      int r = idx >> 4, c4 = (idx & 15) << 2;
      float4 v = *(const float4*)(X + (size_t)(row0 + r) * DIM + k0 + c4);
      bf4_t hx, lx;
      float vv[4] = {v.x, v.y, v.z, v.w};
#pragma unroll
      for (int j = 0; j < 4; ++j) {
        __bf16 hh = (__bf16)vv[j];
        hx[j] = hh; lx[j] = (__bf16)(vv[j] - (float)hh);
      }
      *(bf4_t*)&Xh[r][c4] = hx;
      *(bf4_t*)&Xl[r][c4] = lx;
    }
#pragma unroll
    for (int it = 0; it < 4; ++it) {
      int idx = tid + it * 256;
      int r = idx & 63, c4 = (idx >> 6) << 2;
      float4 v = *(const float4*)(Sb + (size_t)(k0 + r) * SKETCH + c4);
      float vv[4] = {v.x, v.y, v.z, v.w};
#pragma unroll
      for (int j = 0; j < 4; ++j) {
        __bf16 hh = (__bf16)vv[j];
        Sth[c4 + j][r] = hh;
        Stl[c4 + j][r] = (__bf16)(vv[j] - (float)hh);
      }
    }
    __syncthreads();
#pragma unroll
    for (int ks = 0; ks < 4; ++ks) {
      bf8_t ah = *(const bf8_t*)&Xh[w * 32 + l31][ks * 16 + h32 * 8];
      bf8_t al = *(const bf8_t*)&Xl[w * 32 + l31][ks * 16 + h32 * 8];
#pragma unroll
      for (int nt = 0; nt < 2; ++nt) {
        bf8_t bh_ = *(const bf8_t*)&Sth[nt * 32 + l31][ks * 16 + h32 * 8];
        bf8_t bl_ = *(const bf8_t*)&Stl[nt * 32 + l31][ks * 16 + h32 * 8];
        acc[nt] = __builtin_amdgcn_mfma_f32_32x32x16_bf16(ah, bh_, acc[nt], 0, 0, 0);
        acc[nt] = __builtin_amdgcn_mfma_f32_32x32x16_bf16(al, bh_, acc[nt], 0, 0, 0);
        acc[nt] = __builtin_amdgcn_mfma_f32_32x32x16_bf16(ah, bl_, acc[nt], 0, 0, 0);
      }
    }
    __syncthreads();
  }
#pragma unroll
  for (int nt = 0; nt < 2; ++nt)
#pragma unroll
    for (int r = 0; r < 16; ++r) {
      int row = row0 + w * 32 + (r & 3) + 8 * (r >> 2) + 4 * h32;
      atomicAdd(&OUT[(size_t)row * SKETCH + nt * 32 + l31],
                acc[nt][r] * (1.0f / 64.0f));
    }
}

// ---------------------------------------------------------------------------
// proj (MFMA, bf16 hi/lo): C[128 s][64 m] = AS[128x64] @ SB[64x Mout] tile.
// ---------------------------------------------------------------------------
__device__ __forceinline__ void proj_gemm_core(
    const float* __restrict__ ASb, const float* __restrict__ SBb, int Mout,
    int s0, int n0, __bf16* ASh, __bf16* ASl, __bf16* SBth, __bf16* SBtl,
    f32x16_t acc[2]) {
  const int tid = threadIdx.x, ln = tid & 63, w = tid >> 6;
  const int l31 = ln & 31, h32 = ln >> 5;
#pragma unroll
  for (int it = 0; it < 8; ++it) {
    int i = tid + it * 256;
    int r = i >> 4, c4 = (i & 15) << 2;
    float4 v = *(const float4*)(ASb + (size_t)(s0 + r) * SKETCH + c4);
    bf4_t hx, lx;
    float vv[4] = {v.x, v.y, v.z, v.w};
#pragma unroll
    for (int j = 0; j < 4; ++j) {
      __bf16 hh = (__bf16)vv[j];
      hx[j] = hh; lx[j] = (__bf16)(vv[j] - (float)hh);
    }
    *(bf4_t*)&ASh[r * 72 + c4] = hx;
    *(bf4_t*)&ASl[r * 72 + c4] = lx;
  }
#pragma unroll
  for (int it = 0; it < 4; ++it) {
    int i = tid + it * 256;
    int k = i >> 4, c4 = (i & 15) << 2;
    float4 v = *(const float4*)(SBb + (size_t)k * Mout + n0 + c4);
    float vv[4] = {v.x, v.y, v.z, v.w};
#pragma unroll
    for (int j = 0; j < 4; ++j) {
      __bf16 hh = (__bf16)vv[j];
      SBth[(c4 + j) * 72 + k] = hh;
      SBtl[(c4 + j) * 72 + k] = (__bf16)(vv[j] - (float)hh);
    }
  }
  __syncthreads();
#pragma unroll
  for (int ks = 0; ks < 4; ++ks) {
    bf8_t ah = *(const bf8_t*)&ASh[(w * 32 + l31) * 72 + ks * 16 + h32 * 8];
    bf8_t al = *(const bf8_t*)&ASl[(w * 32 + l31) * 72 + ks * 16 + h32 * 8];
#pragma unroll
    for (int nt = 0; nt < 2; ++nt) {
      bf8_t bh_ = *(const bf8_t*)&SBth[(nt * 32 + l31) * 72 + ks * 16 + h32 * 8];
      bf8_t bl_ = *(const bf8_t*)&SBtl[(nt * 32 + l31) * 72 + ks * 16 + h32 * 8];
      acc[nt] = __builtin_amdgcn_mfma_f32_32x32x16_bf16(ah, bh_, acc[nt], 0, 0, 0);
      acc[nt] = __builtin_amdgcn_mfma_f32_32x32x16_bf16(al, bh_, acc[nt], 0, 0, 0);
      acc[nt] = __builtin_amdgcn_mfma_f32_32x32x16_bf16(ah, bl_, acc[nt], 0, 0, 0);
    }
  }
}

// grid(16, 64, 2): y<32 q (rope), y<48 k (rope), else v. Writes fp16 [b][h][s][hd].
__global__ __launch_bounds__(256) void proj_qkv(
    const float* __restrict__ ASq, const float* __restrict__ ASk,
    const float* __restrict__ ASv,
    const float* __restrict__ SBq, const float* __restrict__ SBk,
    const float* __restrict__ SBv,
    const float* __restrict__ freqs,
    _Float16* __restrict__ Qf, _Float16* __restrict__ Kf,
    _Float16* __restrict__ Vf) {
  __shared__ __bf16 ASh[128 * 72], ASl[128 * 72], SBth[64 * 72], SBtl[64 * 72];
  const int b = blockIdx.z, y = blockIdx.y;
  const float *AS, *SB;
  int Mout, nh, mt;
  _Float16* OUT;
  bool rope;
  if (y < 32)      { AS = ASq; SB = SBq; Mout = DIM;    nh = NH;  mt = y;      OUT = Qf; rope = true; }
  else if (y < 48) { AS = ASk; SB = SBk; Mout = KV_DIM; nh = NKV; mt = y - 32; OUT = Kf; rope = true; }
  else             { AS = ASv; SB = SBv; Mout = KV_DIM; nh = NKV; mt = y - 48; OUT = Vf; rope = false; }
  const int s0 = blockIdx.x * 128, n0 = mt * 64;
  f32x16_t acc[2];
#pragma unroll
  for (int nt = 0; nt < 2; ++nt)
#pragma unroll
    for (int r = 0; r < 16; ++r) acc[nt][r] = 0.0f;
  proj_gemm_core(AS + (size_t)b * S_LEN * SKETCH, SB + (size_t)b * SKETCH * Mout,
                 Mout, s0, n0, ASh, ASl, SBth, SBtl, acc);
  const int tid = threadIdx.x, ln = tid & 63, w = tid >> 6;
  const int l31 = ln & 31, h32 = ln >> 5;
  const bool meven = (l31 & 1) == 0;
#pragma unroll
  for (int nt = 0; nt < 2; ++nt) {
    const int m = n0 + nt * 32 + l31;
    const int h = m >> 7, hd = m & (HD - 1);
    const int p = hd >> 1;
#pragma unroll
    for (int r = 0; r < 16; ++r) {
      const int s = s0 + w * 32 + (r & 3) + 8 * (r >> 2) + 4 * h32;
      float v = acc[nt][r];
      float outv;
      if (rope) {
        int pi = __builtin_bit_cast(int, v);
        float part = __builtin_bit_cast(float, __builtin_amdgcn_ds_swizzle(pi, 0x041F));
        float co = freqs[((size_t)s * 64 + p) * 2 + 0];
        float si = freqs[((size_t)s * 64 + p) * 2 + 1];
        outv = meven ? (v * si - part * co) : (part * co + v * si);
      } else {
        outv = v;
      }
      OUT[(((size_t)b * nh + h) * S_LEN + s) * HD + hd] = (_Float16)outv;
    }
  }
}

// grid(16, 32, 2): out[b][s][m] f32
__global__ __launch_bounds__(256) void proj_out(
    const float* __restrict__ ASo, const float* __restrict__ SBo,
    float* __restrict__ out) {
  __shared__ __bf16 ASh[128 * 72], ASl[128 * 72], SBth[64 * 72], SBtl[64 * 72];
  const int b = blockIdx.z;
  const int s0 = blockIdx.x * 128, n0 = blockIdx.y * 64;
  f32x16_t acc[2];
#pragma unroll
  for (int nt = 0; nt < 2; ++nt)
#pragma unroll
    for (int r = 0; r < 16; ++r) acc[nt][r] = 0.0f;
  proj_gemm_core(ASo + (size_t)b * S_LEN * SKETCH, SBo + (size_t)b * SKETCH * DIM,
                 DIM, s0, n0, ASh, ASl, SBth, SBtl, acc);
  const int tid = threadIdx.x, ln = tid & 63, w = tid >> 6;
  const int l31 = ln & 31, h32 = ln >> 5;
#pragma unroll
  for (int nt = 0; nt < 2; ++nt)
#pragma unroll
    for (int r = 0; r < 16; ++r) {
      const int s = s0 + w * 32 + (r & 3) + 8 * (r >> 2) + 4 * h32;
      out[((size_t)b * S_LEN + s) * DIM + n0 + nt * 32 + l31] = acc[nt][r];
    }
}

// ---------------------------------------------------------------------------
// MFMA flash attention v6: split-K x2, KTT=64 (v4's iteration count = 8704,
// the measured dominant term), K tiles in REGISTER FRAGMENTS (A-operand
// layout == coalesced row-major global read; double-buffered ka/kb with
// static alternation; prefetched one full iteration ahead). LDS holds only
// V^T: 2 halves x [128][72] f16 (stride 144 B, baseline's measured-0-conflict
// layout) = 36864 B. launch_bounds(256,2) -> 256-VGPR budget for ~250 live.
// 256 threads = 4 waves: wave w -> q-group wg=w&1 (32 rows), key-half w>>1.
// grid(32 bh, 32 qt): q-tile 64 rows, qt = 31-blockIdx.y (longest first).
// nkt = qt+1 tiles of 64 keys; halves balanced +-1 (nk0=ceil, nk1=floor).
// ---------------------------------------------------------------------------
#define KTT 64
#define VTP 144   // bytes per V^T row (72 halfs)

__device__ __forceinline__ void attn_step(
    const half8_t (&kf)[2][8], const half8_t (&qfr)[8], const char* VtH,
    int k0, int wq_start, int qq, bool hb, int h32, int l31,
    float& mrow, float& lrow, f32x16_t (&o)[4]) {
  // ---- S^T = K Q^T : rows = kk (lane-owned k), cols = qq ----
  f32x16_t sc[2];
#pragma unroll
  for (int nt = 0; nt < 2; ++nt)
#pragma unroll
    for (int r = 0; r < 16; ++r) sc[nt][r] = 0.0f;
#pragma unroll
  for (int ks = 0; ks < 8; ++ks)
#pragma unroll
    for (int nt = 0; nt < 2; ++nt)
      sc[nt] = __builtin_amdgcn_mfma_f32_32x32x16_f16(kf[nt][ks], qfr[ks], sc[nt], 0, 0, 0);
  // ---- scale + causal mask ----
  const bool needMask = (k0 + KTT > wq_start);
#pragma unroll
  for (int nt = 0; nt < 2; ++nt)
#pragma unroll
    for (int r = 0; r < 16; ++r) {
      int kg = k0 + nt * 32 + (r & 3) + 8 * (r >> 2) + 4 * h32;
      float s = sc[nt][r] * SCALE;
      sc[nt][r] = (!needMask || kg <= qq) ? s : -1.0e30f;
    }
  // ---- per-column online softmax with defer-max ----
  float ml = sc[0][0];
#pragma unroll
  for (int r = 1; r < 16; ++r) ml = fmaxf(ml, sc[0][r]);
#pragma unroll
  for (int r = 0; r < 16; ++r) ml = fmaxf(ml, sc[1][r]);
  ml = fmaxf(ml, __shfl_xor(ml, 32));
  if (!__all(ml <= mrow + 8.0f)) {
    float mn = fmaxf(mrow, ml);
    float alpha = __builtin_amdgcn_exp2f(mrow - mn);
    mrow = mn;
    lrow *= alpha;
#pragma unroll
    for (int dt = 0; dt < 4; ++dt)
#pragma unroll
      for (int r = 0; r < 16; ++r) o[dt][r] *= alpha;
  }
  float ps = 0.0f;
#pragma unroll
  for (int nt = 0; nt < 2; ++nt)
#pragma unroll
    for (int r = 0; r < 16; ++r) {
      float p = __builtin_amdgcn_exp2f(sc[nt][r] - mrow);
      sc[nt][r] = p;
      ps += p;
    }
  ps += __shfl_xor(ps, 32);
  lrow += ps;
  // ---- pack P^T to f16 pairs ----
  unsigned int pk[2][8];
#pragma unroll
  for (int nt = 0; nt < 2; ++nt)
#pragma unroll
    for (int gq = 0; gq < 8; ++gq)
      pk[nt][gq] = __builtin_bit_cast(
          unsigned int,
          __builtin_amdgcn_cvt_pkrtz(sc[nt][2 * gq], sc[nt][2 * gq + 1]));
  // ---- PV: O^T += V^T P^T (B-frags via half-wave exchange) ----
#pragma unroll
  for (int ks2 = 0; ks2 < 4; ++ks2) {
    const int nt = ks2 >> 1, a = ks2 & 1;
    unsigned int own0 = hb ? pk[nt][4 * a + 2] : pk[nt][4 * a + 0];
    unsigned int own1 = hb ? pk[nt][4 * a + 3] : pk[nt][4 * a + 1];
    unsigned int oth0 = hb ? pk[nt][4 * a + 0] : pk[nt][4 * a + 2];
    unsigned int oth1 = hb ? pk[nt][4 * a + 1] : pk[nt][4 * a + 3];
    unsigned int rcv0 = __shfl_xor(oth0, 32);
    unsigned int rcv1 = __shfl_xor(oth1, 32);
    uint4_t fu;
    fu.x = hb ? rcv0 : own0;
    fu.y = hb ? rcv1 : own1;
    fu.z = hb ? own0 : rcv0;
    fu.w = hb ? own1 : rcv1;
    half8_t pf16 = __builtin_bit_cast(half8_t, fu);
#pragma unroll
    for (int dt = 0; dt < 4; ++dt) {
      half8_t vf = *(const half8_t*)(
          VtH + (dt * 32 + l31) * VTP + ((ks2 * 16 + h32 * 8) << 1));
      o[dt] = __builtin_amdgcn_mfma_f32_32x32x16_f16(vf, pf16, o[dt], 0, 0, 0);
    }
  }
}

__global__ __launch_bounds__(256, 2) void attn_mfma(
    const _Float16* __restrict__ Qf, const _Float16* __restrict__ Kf,
    const _Float16* __restrict__ Vf, float* __restrict__ O) {
  const int bh = blockIdx.x;
  const int b = bh >> 4, h = bh & 15, g = h >> 1;
  const int qt = 31 - (int)blockIdx.y;
  const int q0 = qt * 64;

  const int tid = threadIdx.x;
  const int ln = tid & 63, w = tid >> 6;       // w in 0..3
  const int wg = w & 1, half = w >> 1;
  const int l31 = ln & 31, h32 = ln >> 5;
  const bool hb = (h32 != 0);

  // [Vt half0: 128x144B][Vt half1: 128x144B] = 36864 B
  __shared__ __align__(16) char smem[36864];
  char* VtH = smem + half * 18432;
  float* Pl = (float*)smem;            // merge scratch [2][64][68] f32 = 34816 B
  float* Ot = (float*)smem;            // epilogue scratch [64][36] f32 = 9216 B

  const _Float16* Kp = Kf + (size_t)(b * NKV + g) * S_LEN * HD;
  const _Float16* Vp = Vf + (size_t)(b * NKV + g) * S_LEN * HD;

  // Q fragments (B-operand for S^T; same lane mapping as A-operand)
  half8_t qfr[8];
  {
    const size_t qrow = (size_t)(b * NH + h) * S_LEN + q0 + wg * 32 + l31;
#pragma unroll
    for (int ks = 0; ks < 8; ++ks)
      qfr[ks] = *(const half8_t*)(Qf + qrow * HD + ks * 16 + h32 * 8);
  }

  float mrow = -1.0e30f, lrow = 0.0f;
  f32x16_t o[4];
#pragma unroll
  for (int dt = 0; dt < 4; ++dt)
#pragma unroll
    for (int r = 0; r < 16; ++r) o[dt][r] = 0.0f;

  const int wq_start = q0 + wg * 32;
  const int qq = wq_start + l31;
  const int nkt = qt + 1;
  const int nk0 = (nkt + 1) >> 1, nk1 = nkt >> 1;

  // K register fragments (per-wave, own half only), double-buffered.
  half8_t ka[2][8], kb[2][8];
  // V staging regs (block-cooperative, both halves): 4 half8 each.
  half8_t vsA[4], vsB[4];

  // K frag load: A-operand layout == row-major global read, per wave.
#define LOADKF(dst, ti)                                                        \
  _Pragma("unroll") for (int nt_ = 0; nt_ < 2; ++nt_)                          \
  _Pragma("unroll") for (int ks_ = 0; ks_ < 8; ++ks_)                          \
    dst[nt_][ks_] = *(const half8_t*)(                                         \
        Kp + (size_t)((ti) * 64 + nt_ * 32 + l31) * HD + ks_ * 16 + h32 * 8);
  // V tile load/store (all 256 threads; 4 half8 per thread per half).
#define LOADVS(dst, ti)                                                        \
  _Pragma("unroll") for (int it_ = 0; it_ < 4; ++it_) {                        \
    int i_ = tid + it_ * 256;                                                  \
    dst[it_] = *(const half8_t*)(                                              \
        Vp + (size_t)((ti) * 64 + (i_ & 63)) * HD + ((i_ >> 6) << 3));         \
  }
#define STOREVS(base, src)                                                     \
  _Pragma("unroll") for (int it_ = 0; it_ < 4; ++it_) {                        \
    int i_ = tid + it_ * 256;                                                  \
    int k_ = i_ & 63, d0_ = (i_ >> 6) << 3;                                    \
    _Pragma("unroll") for (int j_ = 0; j_ < 8; ++j_)                           \
      *(_Float16*)((base) + (d0_ + j_) * VTP + (k_ << 1)) = src[it_][j_];      \
  }

  // ---- prologue: K frags for step 0; V tiles for step 0 ----
  if (!half || nk1 > 0) { LOADKF(ka, half ? nk0 : 0); }
  LOADVS(vsA, 0);
  { const int tB = (nk1 > 0) ? nk0 : 0; LOADVS(vsB, tB); }
  STOREVS(smem, vsA);
  STOREVS(smem + 18432, vsB);
  __syncthreads();

  int i = 0;
  while (true) {
    // ================= even step: compute from ka =================
    {
      const bool pf = (i + 1 < nk0);
      if (pf) {
        if (!half || (i + 1) < nk1) { LOADKF(kb, half ? (nk0 + i + 1) : (i + 1)); }
        LOADVS(vsA, i + 1);
        const int tB = ((i + 1) < nk1) ? (nk0 + i + 1) : (nkt - 1);
        LOADVS(vsB, tB);
      }
      const int t = half ? (nk0 + i) : i;
      const int k0 = t * KTT;
      const bool active = (half ? (i < nk1) : true) && (k0 < wq_start + 32);
      if (active)
        attn_step(ka, qfr, VtH, k0, wq_start, qq, hb, h32, l31, mrow, lrow, o);
      if (pf) {
        __syncthreads();
        STOREVS(smem, vsA);
        STOREVS(smem + 18432, vsB);
        __syncthreads();
      }
    }
    if (++i >= nk0) break;
    // ================= odd step: compute from kb =================
    {
      const bool pf = (i + 1 < nk0);
      if (pf) {
        if (!half || (i + 1) < nk1) { LOADKF(ka, half ? (nk0 + i + 1) : (i + 1)); }
        LOADVS(vsA, i + 1);
        const int tB = ((i + 1) < nk1) ? (nk0 + i + 1) : (nkt - 1);
        LOADVS(vsB, tB);
      }
      const int t = half ? (nk0 + i) : i;
      const int k0 = t * KTT;
      const bool active = (half ? (i < nk1) : true) && (k0 < wq_start + 32);
      if (active)
        attn_step(kb, qfr, VtH, k0, wq_start, qq, hb, h32, l31, mrow, lrow, o);
      if (pf) {
        __syncthreads();
        STOREVS(smem, vsA);
        STOREVS(smem + 18432, vsB);
        __syncthreads();
      }
    }
    if (++i >= nk0) break;
  }

  // ---- merge key-halves: waves 2,3 publish; waves 0,1 combine ----
  __syncthreads();
  if (w >= 2) {
    float* dst = Pl + ((size_t)(w - 2) * 64 + ln) * 68;
#pragma unroll
    for (int dt = 0; dt < 4; ++dt)
#pragma unroll
      for (int gq = 0; gq < 4; ++gq) {
        float4 vv;
        vv.x = o[dt][4 * gq + 0]; vv.y = o[dt][4 * gq + 1];
        vv.z = o[dt][4 * gq + 2]; vv.w = o[dt][4 * gq + 3];
        *(float4*)&dst[dt * 16 + gq * 4] = vv;
      }
    dst[64] = mrow; dst[65] = lrow;
  }
  __syncthreads();
  if (w < 2) {
    const float* src = Pl + ((size_t)w * 64 + ln) * 68;
    float m2 = src[64], l2 = src[65];
    float mn = fmaxf(mrow, m2);
    float a1 = __builtin_amdgcn_exp2f(mrow - mn);
    float a2 = __builtin_amdgcn_exp2f(m2 - mn);
    lrow = lrow * a1 + l2 * a2;
#pragma unroll
    for (int dt = 0; dt < 4; ++dt)
#pragma unroll
      for (int r = 0; r < 16; ++r)
        o[dt][r] = o[dt][r] * a1 + src[dt * 16 + r] * a2;
  }

  // ---- epilogue: O^T[d][qq] -> O[b][s][h*HD+d] via LDS transpose ----
  const float linv = 1.0f / lrow;
  const int s_l = tid >> 5, d_l = tid & 31;   // s_l 0..7
#pragma unroll
  for (int dt = 0; dt < 4; ++dt) {
    __syncthreads();
    if (w < 2) {
#pragma unroll
      for (int gq = 0; gq < 4; ++gq) {
        float4 vv;
        vv.x = o[dt][4 * gq + 0] * linv;
        vv.y = o[dt][4 * gq + 1] * linv;
        vv.z = o[dt][4 * gq + 2] * linv;
        vv.w = o[dt][4 * gq + 3] * linv;
        *(float4*)&Ot[(wg * 32 + l31) * 36 + 8 * gq + 4 * h32] = vv;
      }
    }
    __syncthreads();
#pragma unroll
    for (int ii = 0; ii < 8; ++ii) {
      int s = s_l + 8 * ii;
      float v = Ot[s * 36 + d_l];
      O[((size_t)b * S_LEN + q0 + s) * DIM + h * HD + dt * 32 + d_l] = v;
    }
  }
#undef LOADKF
#undef LOADVS
#undef STOREVS
}

// ---------------------------------------------------------------------------
extern "C" void kernel_launch(void* const* d_in, const int* in_sizes, int n_in,
                              void* d_out, int out_size, void* d_ws, size_t ws_size,
                              hipStream_t stream) {
  const float* x     = (const float*)d_in[0];
  const float* wq    = (const float*)d_in[1];
  const float* wk    = (const float*)d_in[2];
  const float* wv    = (const float*)d_in[3];
  const float* wo    = (const float*)d_in[4];
  const float* Sq    = (const float*)d_in[5];
  const float* Sk    = (const float*)d_in[6];
  const float* Sv    = (const float*)d_in[7];
  const float* So    = (const float*)d_in[8];
  const float* freqs = (const float*)d_in[9];
  float* out = (float*)d_out;

  const size_t AS_E = (size_t)2 * S_LEN * SKETCH;    // 262144
  const size_t SBQ_E = (size_t)2 * SKETCH * DIM;     // 262144
  const size_t SBK_E = (size_t)2 * SKETCH * KV_DIM;  // 131072

  float* fp = (float*)d_ws;
  float* ASq = fp;  fp += AS_E;
  float* ASk = fp;  fp += AS_E;
  float* ASv = fp;  fp += AS_E;
  float* ASo = fp;  fp += AS_E;
  float* SBq = fp;  fp += SBQ_E;
  float* SBk = fp;  fp += SBK_E;
  float* SBv = fp;  fp += SBK_E;
  float* SBo = fp;  fp += SBQ_E;
  float* ATT = fp;  fp += (size_t)2 * S_LEN * DIM;
  _Float16* hp = (_Float16*)fp;
  _Float16* Qfb = hp; hp += (size_t)2 * NH  * S_LEN * HD;
  _Float16* Kfb = hp; hp += (size_t)2 * NKV * S_LEN * HD;
  _Float16* Vfb = hp; hp += (size_t)2 * NKV * S_LEN * HD;

  // zero all atomic-accumulated buffers: 4 AS + 4 SB (contiguous)
  (void)hipMemsetAsync(ASq, 0, (4 * AS_E + 2 * SBQ_E + 2 * SBK_E) * sizeof(float), stream);

  hipLaunchKernelGGL(sbas_mfma, dim3(640), dim3(256), 0, stream,
                     x, Sq, Sk, Sv, So, wq, wk, wv, wo,
                     SBq, SBk, SBv, SBo, ASq, ASk, ASv);
  hipLaunchKernelGGL(proj_qkv, dim3(16, 64, 2), dim3(256), 0, stream,
                     ASq, ASk, ASv, SBq, SBk, SBv, freqs, Qfb, Kfb, Vfb);
  hipLaunchKernelGGL(attn_mfma, dim3(32, 32), dim3(256), 0, stream,
                     Qfb, Kfb, Vfb, ATT);
  hipLaunchKernelGGL(as_mfma, dim3(32, 8), dim3(256), 0, stream, ATT, So, ASo);
  hipLaunchKernelGGL(proj_out, dim3(16, 32, 2), dim3(256), 0, stream, ASo, SBo, out);
}

// Round 8
// 370.788 us; speedup vs baseline: 1.2181x; 1.2181x over previous
//
#include <hip/hip_runtime.h>
#include <math.h>

#define S_LEN 2048
#define DIM   2048
#define NH    16
#define NKV   8
#define HD    128
#define SKETCH 64
#define KV_DIM 1024
// softmax in base-2: fold log2(e) into the score scale
#define SCALE (0.08838834764831845f * 1.4426950408889634f)

typedef _Float16 half8_t  __attribute__((ext_vector_type(8)));
typedef __bf16   bf8_t    __attribute__((ext_vector_type(8)));
typedef __bf16   bf4_t    __attribute__((ext_vector_type(4)));
typedef float    f32x16_t __attribute__((ext_vector_type(16)));
typedef unsigned int uint4_t __attribute__((ext_vector_type(4)));

// ---------------------------------------------------------------------------
// Fused sb_mfma + as_mfma3.  grid(640):
//  x < 384: SB_t[b][k][m] = sum_d S_t[b][d][k] * W_t[m][d]  (atomicAdd, K-split 4)
//  x >= 384: AS_t[row][64] += (1/64) * X[row][:] @ S_t[b][:][:], t in {q,k,v}
// Both roles use the same 55296-byte LDS footprint.
// ---------------------------------------------------------------------------
__global__ __launch_bounds__(256) void sbas_mfma(
    const float* __restrict__ x,
    const float* __restrict__ Sq, const float* __restrict__ Sk,
    const float* __restrict__ Sv, const float* __restrict__ So,
    const float* __restrict__ wq, const float* __restrict__ wk,
    const float* __restrict__ wv, const float* __restrict__ wo,
    float* __restrict__ SBq, float* __restrict__ SBk,
    float* __restrict__ SBv, float* __restrict__ SBo,
    float* __restrict__ ASq, float* __restrict__ ASk,
    float* __restrict__ ASv) {
  __shared__ __align__(16) char smem[55296];
  const int tid = threadIdx.x, ln = tid & 63, w = tid >> 6;
  const int l31 = ln & 31, h32 = ln >> 5;
  const int bx = blockIdx.x;

  if (bx < 384) {
    // ---------------- SB role ----------------
    const int bt = bx % 96, kc = bx / 96;
    const float *Ss, *W;
    float* SB;
    int Mout, n0;
    if (bt < 32)      { Ss = Sq; W = wq; SB = SBq; Mout = DIM;    n0 = bt * 64; }
    else if (bt < 48) { Ss = Sk; W = wk; SB = SBk; Mout = KV_DIM; n0 = (bt - 32) * 64; }
    else if (bt < 64) { Ss = Sv; W = wv; SB = SBv; Mout = KV_DIM; n0 = (bt - 48) * 64; }
    else              { Ss = So; W = wo; SB = SBo; Mout = DIM;    n0 = (bt - 64) * 64; }

    __bf16* Sth = (__bf16*)smem;        // [2][64][72]
    __bf16* Stl = Sth + 9216;
    __bf16* Wh  = Stl + 9216;           // [64][72]
    __bf16* Wl  = Wh + 4608;

    const int bw = w >> 1, mt = w & 1;
    f32x16_t acc[2];
#pragma unroll
    for (int ns = 0; ns < 2; ++ns)
#pragma unroll
      for (int r = 0; r < 16; ++r) acc[ns][r] = 0.0f;

    const int dbeg = kc * 512;
    for (int d0 = dbeg; d0 < dbeg + 512; d0 += 64) {
#pragma unroll
      for (int it = 0; it < 8; ++it) {
        int i = tid + it * 256;
        int b2 = i >> 10, rem = i & 1023;
        int d = rem >> 4, c4 = (rem & 15) << 2;
        float4 v = *(const float4*)(Ss + ((size_t)b2 * DIM + d0 + d) * SKETCH + c4);
        float vv[4] = {v.x, v.y, v.z, v.w};
#pragma unroll
        for (int j = 0; j < 4; ++j) {
          __bf16 hh = (__bf16)vv[j];
          Sth[(b2 * 64 + c4 + j) * 72 + d] = hh;
          Stl[(b2 * 64 + c4 + j) * 72 + d] = (__bf16)(vv[j] - (float)hh);
        }
      }
#pragma unroll
      for (int it = 0; it < 4; ++it) {
        int i = tid + it * 256;
        int c = i >> 4, d4 = (i & 15) << 2;
        float4 v = *(const float4*)(W + (size_t)(n0 + c) * DIM + d0 + d4);
        bf4_t hx, lx;
        float vv[4] = {v.x, v.y, v.z, v.w};
#pragma unroll
        for (int j = 0; j < 4; ++j) {
          __bf16 hh = (__bf16)vv[j];
          hx[j] = hh; lx[j] = (__bf16)(vv[j] - (float)hh);
        }
        *(bf4_t*)&Wh[c * 72 + d4] = hx;
        *(bf4_t*)&Wl[c * 72 + d4] = lx;
      }
      __syncthreads();
#pragma unroll
      for (int ks = 0; ks < 4; ++ks) {
        bf8_t ah = *(const bf8_t*)&Sth[(bw * 64 + mt * 32 + l31) * 72 + ks * 16 + h32 * 8];
        bf8_t al = *(const bf8_t*)&Stl[(bw * 64 + mt * 32 + l31) * 72 + ks * 16 + h32 * 8];
#pragma unroll
        for (int ns = 0; ns < 2; ++ns) {
          bf8_t bh_ = *(const bf8_t*)&Wh[(ns * 32 + l31) * 72 + ks * 16 + h32 * 8];
          bf8_t bl_ = *(const bf8_t*)&Wl[(ns * 32 + l31) * 72 + ks * 16 + h32 * 8];
          acc[ns] = __builtin_amdgcn_mfma_f32_32x32x16_bf16(ah, bh_, acc[ns], 0, 0, 0);
          acc[ns] = __builtin_amdgcn_mfma_f32_32x32x16_bf16(al, bh_, acc[ns], 0, 0, 0);
          acc[ns] = __builtin_amdgcn_mfma_f32_32x32x16_bf16(ah, bl_, acc[ns], 0, 0, 0);
        }
      }
      __syncthreads();
    }
#pragma unroll
    for (int ns = 0; ns < 2; ++ns)
#pragma unroll
      for (int r = 0; r < 16; ++r) {
        int kk = mt * 32 + (r & 3) + 8 * (r >> 2) + 4 * h32;
        atomicAdd(&SB[((size_t)bw * SKETCH + kk) * Mout + n0 + ns * 32 + l31], acc[ns][r]);
      }
  } else {
    // ---------------- AS role ----------------
    const int idx = bx - 384;
    const int rt = idx >> 3, kc = idx & 7;
    const int row0 = rt * 128;
    const int bb = row0 >> 11;

    __bf16* Xh  = (__bf16*)smem;        // [128][72]
    __bf16* Xl  = Xh + 9216;
    __bf16* S2h = Xl + 9216;            // [64][72]
    __bf16* S2l = S2h + 4608;

    const float* Sp[3] = {Sq + (size_t)bb * DIM * SKETCH,
                          Sk + (size_t)bb * DIM * SKETCH,
                          Sv + (size_t)bb * DIM * SKETCH};
    float* Op[3] = {ASq, ASk, ASv};

    f32x16_t acc[3][2];
#pragma unroll
    for (int t = 0; t < 3; ++t)
#pragma unroll
      for (int nt = 0; nt < 2; ++nt)
#pragma unroll
        for (int r = 0; r < 16; ++r) acc[t][nt][r] = 0.0f;

    const int kbeg = kc * 256;
    for (int k0 = kbeg; k0 < kbeg + 256; k0 += 64) {
#pragma unroll
      for (int it = 0; it < 8; ++it) {
        int i = tid + it * 256;
        int r = i >> 4, c4 = (i & 15) << 2;
        float4 v = *(const float4*)(x + (size_t)(row0 + r) * DIM + k0 + c4);
        bf4_t hx, lx;
        float vv[4] = {v.x, v.y, v.z, v.w};
#pragma unroll
        for (int j = 0; j < 4; ++j) {
          __bf16 hh = (__bf16)vv[j];
          hx[j] = hh; lx[j] = (__bf16)(vv[j] - (float)hh);
        }
        *(bf4_t*)&Xh[r * 72 + c4] = hx;
        *(bf4_t*)&Xl[r * 72 + c4] = lx;
      }
#pragma unroll
      for (int t = 0; t < 3; ++t) {
#pragma unroll
        for (int it = 0; it < 4; ++it) {
          int i = tid + it * 256;
          int r = i & 63, c4 = (i >> 6) << 2;
          float4 v = *(const float4*)(Sp[t] + (size_t)(k0 + r) * SKETCH + c4);
          float vv[4] = {v.x, v.y, v.z, v.w};
#pragma unroll
          for (int j = 0; j < 4; ++j) {
            __bf16 hh = (__bf16)vv[j];
            S2h[(c4 + j) * 72 + r] = hh;
            S2l[(c4 + j) * 72 + r] = (__bf16)(vv[j] - (float)hh);
          }
        }
        __syncthreads();
#pragma unroll
        for (int ks = 0; ks < 4; ++ks) {
          bf8_t ah = *(const bf8_t*)&Xh[(w * 32 + l31) * 72 + ks * 16 + h32 * 8];
          bf8_t al = *(const bf8_t*)&Xl[(w * 32 + l31) * 72 + ks * 16 + h32 * 8];
#pragma unroll
          for (int nt = 0; nt < 2; ++nt) {
            bf8_t bh_ = *(const bf8_t*)&S2h[(nt * 32 + l31) * 72 + ks * 16 + h32 * 8];
            bf8_t bl_ = *(const bf8_t*)&S2l[(nt * 32 + l31) * 72 + ks * 16 + h32 * 8];
            acc[t][nt] = __builtin_amdgcn_mfma_f32_32x32x16_bf16(ah, bh_, acc[t][nt], 0, 0, 0);
            acc[t][nt] = __builtin_amdgcn_mfma_f32_32x32x16_bf16(al, bh_, acc[t][nt], 0, 0, 0);
            acc[t][nt] = __builtin_amdgcn_mfma_f32_32x32x16_bf16(ah, bl_, acc[t][nt], 0, 0, 0);
          }
        }
        __syncthreads();
      }
    }
#pragma unroll
    for (int t = 0; t < 3; ++t)
#pragma unroll
      for (int nt = 0; nt < 2; ++nt)
#pragma unroll
        for (int r = 0; r < 16; ++r) {
          int row = row0 + w * 32 + (r & 3) + 8 * (r >> 2) + 4 * h32;
          atomicAdd(&Op[t][(size_t)row * SKETCH + nt * 32 + l31],
                    acc[t][nt][r] * (1.0f / 64.0f));
        }
  }
}

// ---------------------------------------------------------------------------
// as_mfma: single-matrix version (ATT @ So), unchanged.
// ---------------------------------------------------------------------------
__global__ __launch_bounds__(256) void as_mfma(
    const float* __restrict__ X, const float* __restrict__ S,
    float* __restrict__ OUT) {
  const int rt = blockIdx.x, kc = blockIdx.y;
  const int row0 = rt * 128;
  const int bb = row0 >> 11;
  const float* Sb = S + (size_t)bb * DIM * SKETCH;
  const int tid = threadIdx.x, ln = tid & 63, w = tid >> 6;
  const int l31 = ln & 31, h32 = ln >> 5;

  __shared__ __bf16 Xh[128][72], Xl[128][72];
  __shared__ __bf16 Sth[64][72], Stl[64][72];

  f32x16_t acc[2];
#pragma unroll
  for (int nt = 0; nt < 2; ++nt)
#pragma unroll
    for (int r = 0; r < 16; ++r) acc[nt][r] = 0.0f;

  const int kbeg = kc * 256;
  for (int k0 = kbeg; k0 < kbeg + 256; k0 += 64) {
#pragma unroll
    for (int it = 0; it < 8; ++it) {
      int idx = tid + it * 256;
      int r = idx >> 4, c4 = (idx & 15) << 2;
      float4 v = *(const float4*)(X + (size_t)(row0 + r) * DIM + k0 + c4);
      bf4_t hx, lx;
      float vv[4] = {v.x, v.y, v.z, v.w};
#pragma unroll
      for (int j = 0; j < 4; ++j) {
        __bf16 hh = (__bf16)vv[j];
        hx[j] = hh; lx[j] = (__bf16)(vv[j] - (float)hh);
      }
      *(bf4_t*)&Xh[r][c4] = hx;
      *(bf4_t*)&Xl[r][c4] = lx;
    }
#pragma unroll
    for (int it = 0; it < 4; ++it) {
      int idx = tid + it * 256;
      int r = idx & 63, c4 = (idx >> 6) << 2;
      float4 v = *(const float4*)(Sb + (size_t)(k0 + r) * SKETCH + c4);
      float vv[4] = {v.x, v.y, v.z, v.w};
#pragma unroll
      for (int j = 0; j < 4; ++j) {
        __bf16 hh = (__bf16)vv[j];
        Sth[c4 + j][r] = hh;
        Stl[c4 + j][r] = (__bf16)(vv[j] - (float)hh);
      }
    }
    __syncthreads();
#pragma unroll
    for (int ks = 0; ks < 4; ++ks) {
      bf8_t ah = *(const bf8_t*)&Xh[w * 32 + l31][ks * 16 + h32 * 8];
      bf8_t al = *(const bf8_t*)&Xl[w * 32 + l31][ks * 16 + h32 * 8];
#pragma unroll
      for (int nt = 0; nt < 2; ++nt) {
        bf8_t bh_ = *(const bf8_t*)&Sth[nt * 32 + l31][ks * 16 + h32 * 8];
        bf8_t bl_ = *(const bf8_t*)&Stl[nt * 32 + l31][ks * 16 + h32 * 8];
        acc[nt] = __builtin_amdgcn_mfma_f32_32x32x16_bf16(ah, bh_, acc[nt], 0, 0, 0);
        acc[nt] = __builtin_amdgcn_mfma_f32_32x32x16_bf16(al, bh_, acc[nt], 0, 0, 0);
        acc[nt] = __builtin_amdgcn_mfma_f32_32x32x16_bf16(ah, bl_, acc[nt], 0, 0, 0);
      }
    }
    __syncthreads();
  }
#pragma unroll
  for (int nt = 0; nt < 2; ++nt)
#pragma unroll
    for (int r = 0; r < 16; ++r) {
      int row = row0 + w * 32 + (r & 3) + 8 * (r >> 2) + 4 * h32;
      atomicAdd(&OUT[(size_t)row * SKETCH + nt * 32 + l31],
                acc[nt][r] * (1.0f / 64.0f));
    }
}

// ---------------------------------------------------------------------------
// proj (MFMA, bf16 hi/lo): C[128 s][64 m] = AS[128x64] @ SB[64x Mout] tile.
// ---------------------------------------------------------------------------
__device__ __forceinline__ void proj_gemm_core(
    const float* __restrict__ ASb, const float* __restrict__ SBb, int Mout,
    int s0, int n0, __bf16* ASh, __bf16* ASl, __bf16* SBth, __bf16* SBtl,
    f32x16_t acc[2]) {
  const int tid = threadIdx.x, ln = tid & 63, w = tid >> 6;
  const int l31 = ln & 31, h32 = ln >> 5;
#pragma unroll
  for (int it = 0; it < 8; ++it) {
    int i = tid + it * 256;
    int r = i >> 4, c4 = (i & 15) << 2;
    float4 v = *(const float4*)(ASb + (size_t)(s0 + r) * SKETCH + c4);
    bf4_t hx, lx;
    float vv[4] = {v.x, v.y, v.z, v.w};
#pragma unroll
    for (int j = 0; j < 4; ++j) {
      __bf16 hh = (__bf16)vv[j];
      hx[j] = hh; lx[j] = (__bf16)(vv[j] - (float)hh);
    }
    *(bf4_t*)&ASh[r * 72 + c4] = hx;
    *(bf4_t*)&ASl[r * 72 + c4] = lx;
  }
#pragma unroll
  for (int it = 0; it < 4; ++it) {
    int i = tid + it * 256;
    int k = i >> 4, c4 = (i & 15) << 2;
    float4 v = *(const float4*)(SBb + (size_t)k * Mout + n0 + c4);
    float vv[4] = {v.x, v.y, v.z, v.w};
#pragma unroll
    for (int j = 0; j < 4; ++j) {
      __bf16 hh = (__bf16)vv[j];
      SBth[(c4 + j) * 72 + k] = hh;
      SBtl[(c4 + j) * 72 + k] = (__bf16)(vv[j] - (float)hh);
    }
  }
  __syncthreads();
#pragma unroll
  for (int ks = 0; ks < 4; ++ks) {
    bf8_t ah = *(const bf8_t*)&ASh[(w * 32 + l31) * 72 + ks * 16 + h32 * 8];
    bf8_t al = *(const bf8_t*)&ASl[(w * 32 + l31) * 72 + ks * 16 + h32 * 8];
#pragma unroll
    for (int nt = 0; nt < 2; ++nt) {
      bf8_t bh_ = *(const bf8_t*)&SBth[(nt * 32 + l31) * 72 + ks * 16 + h32 * 8];
      bf8_t bl_ = *(const bf8_t*)&SBtl[(nt * 32 + l31) * 72 + ks * 16 + h32 * 8];
      acc[nt] = __builtin_amdgcn_mfma_f32_32x32x16_bf16(ah, bh_, acc[nt], 0, 0, 0);
      acc[nt] = __builtin_amdgcn_mfma_f32_32x32x16_bf16(al, bh_, acc[nt], 0, 0, 0);
      acc[nt] = __builtin_amdgcn_mfma_f32_32x32x16_bf16(ah, bl_, acc[nt], 0, 0, 0);
    }
  }
}

// grid(16, 64, 2): y<32 q (rope), y<48 k (rope), else v. Writes fp16 [b][h][s][hd].
__global__ __launch_bounds__(256) void proj_qkv(
    const float* __restrict__ ASq, const float* __restrict__ ASk,
    const float* __restrict__ ASv,
    const float* __restrict__ SBq, const float* __restrict__ SBk,
    const float* __restrict__ SBv,
    const float* __restrict__ freqs,
    _Float16* __restrict__ Qf, _Float16* __restrict__ Kf,
    _Float16* __restrict__ Vf) {
  __shared__ __bf16 ASh[128 * 72], ASl[128 * 72], SBth[64 * 72], SBtl[64 * 72];
  const int b = blockIdx.z, y = blockIdx.y;
  const float *AS, *SB;
  int Mout, nh, mt;
  _Float16* OUT;
  bool rope;
  if (y < 32)      { AS = ASq; SB = SBq; Mout = DIM;    nh = NH;  mt = y;      OUT = Qf; rope = true; }
  else if (y < 48) { AS = ASk; SB = SBk; Mout = KV_DIM; nh = NKV; mt = y - 32; OUT = Kf; rope = true; }
  else             { AS = ASv; SB = SBv; Mout = KV_DIM; nh = NKV; mt = y - 48; OUT = Vf; rope = false; }
  const int s0 = blockIdx.x * 128, n0 = mt * 64;
  f32x16_t acc[2];
#pragma unroll
  for (int nt = 0; nt < 2; ++nt)
#pragma unroll
    for (int r = 0; r < 16; ++r) acc[nt][r] = 0.0f;
  proj_gemm_core(AS + (size_t)b * S_LEN * SKETCH, SB + (size_t)b * SKETCH * Mout,
                 Mout, s0, n0, ASh, ASl, SBth, SBtl, acc);
  const int tid = threadIdx.x, ln = tid & 63, w = tid >> 6;
  const int l31 = ln & 31, h32 = ln >> 5;
  const bool meven = (l31 & 1) == 0;
#pragma unroll
  for (int nt = 0; nt < 2; ++nt) {
    const int m = n0 + nt * 32 + l31;
    const int h = m >> 7, hd = m & (HD - 1);
    const int p = hd >> 1;
#pragma unroll
    for (int r = 0; r < 16; ++r) {
      const int s = s0 + w * 32 + (r & 3) + 8 * (r >> 2) + 4 * h32;
      float v = acc[nt][r];
      float outv;
      if (rope) {
        int pi = __builtin_bit_cast(int, v);
        float part = __builtin_bit_cast(float, __builtin_amdgcn_ds_swizzle(pi, 0x041F));
        float co = freqs[((size_t)s * 64 + p) * 2 + 0];
        float si = freqs[((size_t)s * 64 + p) * 2 + 1];
        outv = meven ? (v * si - part * co) : (part * co + v * si);
      } else {
        outv = v;
      }
      OUT[(((size_t)b * nh + h) * S_LEN + s) * HD + hd] = (_Float16)outv;
    }
  }
}

// grid(16, 32, 2): out[b][s][m] f32
__global__ __launch_bounds__(256) void proj_out(
    const float* __restrict__ ASo, const float* __restrict__ SBo,
    float* __restrict__ out) {
  __shared__ __bf16 ASh[128 * 72], ASl[128 * 72], SBth[64 * 72], SBtl[64 * 72];
  const int b = blockIdx.z;
  const int s0 = blockIdx.x * 128, n0 = blockIdx.y * 64;
  f32x16_t acc[2];
#pragma unroll
  for (int nt = 0; nt < 2; ++nt)
#pragma unroll
    for (int r = 0; r < 16; ++r) acc[nt][r] = 0.0f;
  proj_gemm_core(ASo + (size_t)b * S_LEN * SKETCH, SBo + (size_t)b * SKETCH * DIM,
                 DIM, s0, n0, ASh, ASl, SBth, SBtl, acc);
  const int tid = threadIdx.x, ln = tid & 63, w = tid >> 6;
  const int l31 = ln & 31, h32 = ln >> 5;
#pragma unroll
  for (int nt = 0; nt < 2; ++nt)
#pragma unroll
    for (int r = 0; r < 16; ++r) {
      const int s = s0 + w * 32 + (r & 3) + 8 * (r >> 2) + 4 * h32;
      out[((size_t)b * S_LEN + s) * DIM + n0 + nt * 32 + l31] = acc[nt][r];
    }
}

// ---------------------------------------------------------------------------
// MFMA flash attention v2 (BASELINE, 112 µs measured): S^T formulation
// (lane = q-column softmax), register prefetch of K/V tiles, P^T exchanged
// in-register (no P LDS). grid(16, 32): x -> q-tile (128 rows,
// longest-first), y = b*16 + h.
// Reverted here after 4 split-K redesigns (v3-v6) all lost to it:
// the VGPR allocator pins this loop shape at <=128 regs, so any variant
// holding 2 K-tile buffers + split-K state spills to scratch (98-280 MB
// measured), and halving KTT doubles iteration overhead. See journal.
// ---------------------------------------------------------------------------
#define QTT 128
#define KTT 64
#define KP  136   // halfs per K row (272 B)
#define VP  72    // halfs per Vt row (144 B)

__global__ __launch_bounds__(256, 2) void attn_mfma(
    const _Float16* __restrict__ Qf, const _Float16* __restrict__ Kf,
    const _Float16* __restrict__ Vf, float* __restrict__ O) {
  const int bh = blockIdx.y;
  const int b = bh >> 4, h = bh & 15, g = h >> 1;
  const int qt = 15 - (int)blockIdx.x;
  const int q0 = qt * QTT;

  const int tid = threadIdx.x;
  const int ln = tid & 63, w = tid >> 6;
  const int l31 = ln & 31, h32 = ln >> 5;
  const bool hb = (h32 != 0);

  __shared__ _Float16 Ks[KTT][KP];     // 17408 B
  __shared__ _Float16 Vts[HD][VP];     // 18432 B (epilogue overlay: float[128][36])
  float* Ot = (float*)&Vts[0][0];

  const _Float16* Kp = Kf + (size_t)(b * NKV + g) * S_LEN * HD;
  const _Float16* Vp = Vf + (size_t)(b * NKV + g) * S_LEN * HD;

  // Q fragments (B-operand for S^T; same lane mapping as A-operand)
  half8_t qfr[8];
  {
    const size_t qrow = (size_t)(b * NH + h) * S_LEN + q0 + w * 32 + l31;
#pragma unroll
    for (int ks = 0; ks < 8; ++ks)
      qfr[ks] = *(const half8_t*)(Qf + qrow * HD + ks * 16 + h32 * 8);
  }

  float mrow = -1.0e30f, lrow = 0.0f;
  f32x16_t o[4];
#pragma unroll
  for (int dt = 0; dt < 4; ++dt)
#pragma unroll
    for (int r = 0; r < 16; ++r) o[dt][r] = 0.0f;

  const int wq_start = q0 + w * 32;
  const int qq = wq_start + l31;
  const int nkt = 2 * qt + 2;

  half8_t kreg[4], vreg[4];
  // preload tile 0
#pragma unroll
  for (int it = 0; it < 4; ++it) {
    int i = tid + it * 256;
    kreg[it] = *(const half8_t*)(Kp + (size_t)(i >> 4) * HD + ((i & 15) << 3));
    vreg[it] = *(const half8_t*)(Vp + (size_t)(i & 63) * HD + (((i >> 6) << 3)));
  }
  // store tile 0
#pragma unroll
  for (int it = 0; it < 4; ++it) {
    int i = tid + it * 256;
    *(half8_t*)&Ks[i >> 4][(i & 15) << 3] = kreg[it];
    int k = i & 63, d0 = (i >> 6) << 3;
#pragma unroll
    for (int j = 0; j < 8; ++j) Vts[d0 + j][k] = vreg[it][j];
  }
  __syncthreads();

  for (int kt = 0; kt < nkt; ++kt) {
    const int k0 = kt * KTT;
    // prefetch next tile into registers (latency hidden behind compute)
    if (kt + 1 < nkt) {
      const int kn = k0 + KTT;
#pragma unroll
      for (int it = 0; it < 4; ++it) {
        int i = tid + it * 256;
        kreg[it] = *(const half8_t*)(Kp + (size_t)(kn + (i >> 4)) * HD + ((i & 15) << 3));
        vreg[it] = *(const half8_t*)(Vp + (size_t)(kn + (i & 63)) * HD + (((i >> 6) << 3)));
      }
    }

    if (k0 < wq_start + 32) {  // wave-uniform activity
      // ---- S^T = K Q^T : rows = kk, cols = qq (lane-owned) ----
      f32x16_t sc[2];
#pragma unroll
      for (int nt = 0; nt < 2; ++nt)
#pragma unroll
        for (int r = 0; r < 16; ++r) sc[nt][r] = 0.0f;
#pragma unroll
      for (int ks = 0; ks < 8; ++ks)
#pragma unroll
        for (int nt = 0; nt < 2; ++nt) {
          half8_t kf = *(const half8_t*)&Ks[nt * 32 + l31][ks * 16 + h32 * 8];
          sc[nt] = __builtin_amdgcn_mfma_f32_32x32x16_f16(kf, qfr[ks], sc[nt], 0, 0, 0);
        }
      // ---- scale + causal mask ----
      const bool needMask = (k0 + KTT > wq_start);
#pragma unroll
      for (int nt = 0; nt < 2; ++nt)
#pragma unroll
        for (int r = 0; r < 16; ++r) {
          int kg = k0 + nt * 32 + (r & 3) + 8 * (r >> 2) + 4 * h32;
          float s = sc[nt][r] * SCALE;
          sc[nt][r] = (!needMask || kg <= qq) ? s : -1.0e30f;
        }
      // ---- per-column online softmax (in-lane + one xor-32) ----
      float ml = sc[0][0];
#pragma unroll
      for (int r = 1; r < 16; ++r) ml = fmaxf(ml, sc[0][r]);
#pragma unroll
      for (int r = 0; r < 16; ++r) ml = fmaxf(ml, sc[1][r]);
      ml = fmaxf(ml, __shfl_xor(ml, 32));
      float mn = fmaxf(mrow, ml);
      float alpha = __builtin_amdgcn_exp2f(mrow - mn);
      mrow = mn;
      float ps = 0.0f;
#pragma unroll
      for (int nt = 0; nt < 2; ++nt)
#pragma unroll
        for (int r = 0; r < 16; ++r) {
          float p = __builtin_amdgcn_exp2f(sc[nt][r] - mn);
          sc[nt][r] = p;
          ps += p;
        }
      ps += __shfl_xor(ps, 32);
      lrow = lrow * alpha + ps;
#pragma unroll
      for (int dt = 0; dt < 4; ++dt)
#pragma unroll
        for (int r = 0; r < 16; ++r) o[dt][r] *= alpha;

      // ---- pack P^T to f16 pairs ----
      unsigned int pk[2][8];
#pragma unroll
      for (int nt = 0; nt < 2; ++nt)
#pragma unroll
        for (int gq = 0; gq < 8; ++gq)
          pk[nt][gq] = __builtin_bit_cast(
              unsigned int,
              __builtin_amdgcn_cvt_pkrtz(sc[nt][2 * gq], sc[nt][2 * gq + 1]));
      // ---- PV: O^T += V^T P^T  (B-frags via half-wave exchange) ----
#pragma unroll
      for (int ks2 = 0; ks2 < 4; ++ks2) {
        const int nt = ks2 >> 1, a = ks2 & 1;
        unsigned int own0 = hb ? pk[nt][4 * a + 2] : pk[nt][4 * a + 0];
        unsigned int own1 = hb ? pk[nt][4 * a + 3] : pk[nt][4 * a + 1];
        unsigned int oth0 = hb ? pk[nt][4 * a + 0] : pk[nt][4 * a + 2];
        unsigned int oth1 = hb ? pk[nt][4 * a + 1] : pk[nt][4 * a + 3];
        unsigned int rcv0 = __shfl_xor(oth0, 32);
        unsigned int rcv1 = __shfl_xor(oth1, 32);
        uint4_t fu;
        fu.x = hb ? rcv0 : own0;
        fu.y = hb ? rcv1 : own1;
        fu.z = hb ? own0 : rcv0;
        fu.w = hb ? own1 : rcv1;
        half8_t pf = __builtin_bit_cast(half8_t, fu);
#pragma unroll
        for (int dt = 0; dt < 4; ++dt) {
          half8_t vf = *(const half8_t*)&Vts[dt * 32 + l31][ks2 * 16 + h32 * 8];
          o[dt] = __builtin_amdgcn_mfma_f32_32x32x16_f16(vf, pf, o[dt], 0, 0, 0);
        }
      }
    }

    if (kt + 1 < nkt) {
      __syncthreads();  // everyone done reading Ks/Vts
#pragma unroll
      for (int it = 0; it < 4; ++it) {
        int i = tid + it * 256;
        *(half8_t*)&Ks[i >> 4][(i & 15) << 3] = kreg[it];
        int k = i & 63, d0 = (i >> 6) << 3;
#pragma unroll
        for (int j = 0; j < 8; ++j) Vts[d0 + j][k] = vreg[it][j];
      }
      __syncthreads();
    }
  }

  // ---- epilogue: O^T[d][qq] -> O[b][s][h*HD+d] via LDS transpose ----
  const float linv = 1.0f / lrow;
  const int s_l = tid >> 5, d_l = tid & 31;
#pragma unroll
  for (int dt = 0; dt < 4; ++dt) {
    __syncthreads();
#pragma unroll
    for (int gq = 0; gq < 4; ++gq) {
      float4 vv;
      vv.x = o[dt][4 * gq + 0] * linv;
      vv.y = o[dt][4 * gq + 1] * linv;
      vv.z = o[dt][4 * gq + 2] * linv;
      vv.w = o[dt][4 * gq + 3] * linv;
      *(float4*)&Ot[(w * 32 + l31) * 36 + 8 * gq + 4 * h32] = vv;
    }
    __syncthreads();
#pragma unroll
    for (int i = 0; i < 16; ++i) {
      int s = s_l + 8 * i;
      float v = Ot[s * 36 + d_l];
      O[((size_t)b * S_LEN + q0 + s) * DIM + h * HD + dt * 32 + d_l] = v;
    }
  }
}

// ---------------------------------------------------------------------------
extern "C" void kernel_launch(void* const* d_in, const int* in_sizes, int n_in,
                              void* d_out, int out_size, void* d_ws, size_t ws_size,
                              hipStream_t stream) {
  const float* x     = (const float*)d_in[0];
  const float* wq    = (const float*)d_in[1];
  const float* wk    = (const float*)d_in[2];
  const float* wv    = (const float*)d_in[3];
  const float* wo    = (const float*)d_in[4];
  const float* Sq    = (const float*)d_in[5];
  const float* Sk    = (const float*)d_in[6];
  const float* Sv    = (const float*)d_in[7];
  const float* So    = (const float*)d_in[8];
  const float* freqs = (const float*)d_in[9];
  float* out = (float*)d_out;

  const size_t AS_E = (size_t)2 * S_LEN * SKETCH;    // 262144
  const size_t SBQ_E = (size_t)2 * SKETCH * DIM;     // 262144
  const size_t SBK_E = (size_t)2 * SKETCH * KV_DIM;  // 131072

  float* fp = (float*)d_ws;
  float* ASq = fp;  fp += AS_E;
  float* ASk = fp;  fp += AS_E;
  float* ASv = fp;  fp += AS_E;
  float* ASo = fp;  fp += AS_E;
  float* SBq = fp;  fp += SBQ_E;
  float* SBk = fp;  fp += SBK_E;
  float* SBv = fp;  fp += SBK_E;
  float* SBo = fp;  fp += SBQ_E;
  float* ATT = fp;  fp += (size_t)2 * S_LEN * DIM;
  _Float16* hp = (_Float16*)fp;
  _Float16* Qfb = hp; hp += (size_t)2 * NH  * S_LEN * HD;
  _Float16* Kfb = hp; hp += (size_t)2 * NKV * S_LEN * HD;
  _Float16* Vfb = hp; hp += (size_t)2 * NKV * S_LEN * HD;

  // zero all atomic-accumulated buffers: 4 AS + 4 SB (contiguous)
  (void)hipMemsetAsync(ASq, 0, (4 * AS_E + 2 * SBQ_E + 2 * SBK_E) * sizeof(float), stream);

  hipLaunchKernelGGL(sbas_mfma, dim3(640), dim3(256), 0, stream,
                     x, Sq, Sk, Sv, So, wq, wk, wv, wo,
                     SBq, SBk, SBv, SBo, ASq, ASk, ASv);
  hipLaunchKernelGGL(proj_qkv, dim3(16, 64, 2), dim3(256), 0, stream,
                     ASq, ASk, ASv, SBq, SBk, SBv, freqs, Qfb, Kfb, Vfb);
  hipLaunchKernelGGL(attn_mfma, dim3(16, 32), dim3(256), 0, stream,
                     Qfb, Kfb, Vfb, ATT);
  hipLaunchKernelGGL(as_mfma, dim3(32, 8), dim3(256), 0, stream, ATT, So, ASo);
  hipLaunchKernelGGL(proj_out, dim3(16, 32, 2), dim3(256), 0, stream, ASo, SBo, out);
}